// Round 9
// baseline (784.615 us; speedup 1.0000x reference)
//
#include <hip/hip_runtime.h>

// ---------------- problem constants ----------------
#define NNODES 20000
#define NEDGES 320000
#define NELEM  10
#define NC     (NNODES * 64)   // 1,280,000

// ---------------- phase-overlaid ws layout (float offsets) ----------------
#define OFF_SUP1 ((size_t)0)
#define OFF_AGS1 ((size_t)1 * NC)
#define OFF_AGV1 ((size_t)2 * NC)
#define OFF_AGS2 ((size_t)0)
#define OFF_AGV2 ((size_t)2 * NC)
#define OFF_SUP2 ((size_t)8 * NC)
#define OFF_VUP2 ((size_t)9 * NC)
#define OFF_SKS2 ((size_t)12 * NC)
#define OFF_SKV2 ((size_t)13 * NC)
#define OFF_INT  ((size_t)16 * NC)

// __expf: rel err ~2^-21, fine at 20x accuracy margin
__device__ __forceinline__ float silu(float x) { return x / (1.0f + __expf(-x)); }
__device__ __forceinline__ int rfl(int v) { return __builtin_amdgcn_readfirstlane(v); }
// per-edge uniforms via v_readlane from lane-resident registers (no LDS latency)
__device__ __forceinline__ int rl_i(int v, int l) { return __builtin_amdgcn_readlane(v, l); }
__device__ __forceinline__ float rl_f(float v, int l) {
    return __int_as_float(__builtin_amdgcn_readlane(__float_as_int(v), l));
}

// ---------------- sort by rcv: histogram ----------------
__global__ __launch_bounds__(256) void k_hist(const int* __restrict__ eidx,
                                              int* __restrict__ hist)
{
    int e = blockIdx.x * 256 + threadIdx.x;
    atomicAdd(&hist[eidx[NEDGES + e]], 1);
}

// ---------------- sort by rcv: exclusive scan (1 block, shfl-based) ----------------
__global__ __launch_bounds__(1024) void k_scan(const int* __restrict__ hist,
                                               int* __restrict__ cursor)
{
    __shared__ int wsum[16];
    __shared__ int gbase;
    int tid = threadIdx.x;
    int lane = tid & 63, wvid = tid >> 6;
    if (tid == 0) gbase = 0;
    __syncthreads();
    for (int seg = 0; seg < 20; ++seg) {
        int i = seg * 1024 + tid;
        int v = (i < NNODES) ? hist[i] : 0;
        int s = v;
        #pragma unroll
        for (int d = 1; d < 64; d <<= 1) {
            int t = __shfl_up(s, d, 64);
            if (lane >= d) s += t;
        }
        if (lane == 63) wsum[wvid] = s;
        __syncthreads();
        if (wvid == 0) {
            int w = (lane < 16) ? wsum[lane] : 0;
            #pragma unroll
            for (int d = 1; d < 16; d <<= 1) {
                int t = __shfl_up(w, d, 64);
                if (lane >= d) w += t;
            }
            if (lane < 16) wsum[lane] = w;
        }
        __syncthreads();
        int wbase = (wvid == 0) ? 0 : wsum[wvid - 1];
        if (i < NNODES) cursor[i] = gbase + wbase + s - v;
        int segtot = wsum[15];
        __syncthreads();
        if (tid == 0) gbase += segtot;
    }
}

// ---------------- sort by rcv: scatter ----------------
__global__ __launch_bounds__(256) void k_scatter(const int* __restrict__ eidx,
                                                 int* __restrict__ cursor,
                                                 int* __restrict__ sorted)
{
    int e = blockIdx.x * 256 + threadIdx.x;
    int pos = atomicAdd(&cursor[eidx[NEDGES + e]], 1);
    sorted[pos] = e;
}

// ---------------- edge geometry helper ----------------
__device__ __forceinline__ void edge_geom(
    int e, const float* __restrict__ pos, const int* __restrict__ eidx,
    const float* __restrict__ shf, int* snd_out, int* rcv_out,
    float feats[8], float y[3])
{
    int snd = eidx[e], rcv = eidx[NEDGES + e];
    *snd_out = snd; *rcv_out = rcv;
    float dx = pos[snd * 3 + 0] - pos[rcv * 3 + 0] + shf[(size_t)e * 3 + 0];
    float dy = pos[snd * 3 + 1] - pos[rcv * 3 + 1] + shf[(size_t)e * 3 + 1];
    float dz = pos[snd * 3 + 2] - pos[rcv * 3 + 2] + shf[(size_t)e * 3 + 2];
    float len = sqrtf(dx * dx + dy * dy + dz * dz + 1e-12f);
    float inv = 1.0f / len;
    float u = len * 0.2f;
    float u2 = u * u, u4 = u2 * u2, u5 = u4 * u, u6 = u5 * u, u7 = u6 * u;
    float cut = (u < 1.0f) ? (1.0f - 21.0f * u5 + 35.0f * u6 - 15.0f * u7) : 0.0f;
    float s = 0.632455532033676f * inv * cut;   // sqrt(2/5)/len * cutoff
    #pragma unroll
    for (int k = 0; k < 8; ++k)
        feats[k] = s * sinf((float)(k + 1) * 0.628318530717959f * len);
    y[0] = 1.73205080756888f * dx * inv;
    y[1] = 1.73205080756888f * dy * inv;
    y[2] = 1.73205080756888f * dz * inv;
}

// ---------------- node pre: sUp1 = (attrs @ W_embed) @ U1_s ----------------
__global__ __launch_bounds__(256) void k_node_pre(
    const float* __restrict__ attrs, const float* __restrict__ Wemb,
    const float* __restrict__ U1s, float* __restrict__ sUp1)
{
    int lane = threadIdx.x & 63, wv = threadIdx.x >> 6;
    int n = blockIdx.x * 4 + wv;
    __shared__ __align__(16) float s0sh[4][64];
    float s0 = 0.f;
    #pragma unroll
    for (int v = 0; v < NELEM; ++v) s0 += attrs[n * NELEM + v] * Wemb[v * 64 + lane];
    s0sh[wv][lane] = s0;
    __syncthreads();
    float a = 0.f;
    #pragma unroll 8
    for (int k = 0; k < 64; ++k) a += s0sh[wv][k] * U1s[k * 64 + lane];
    sUp1[n * 64 + lane] = a;
}

// ---------------- edge block 1 ----------------
// 64 edges/block, 4 waves. mu -> (m = mu&1 slice, hh = mu>>1).
__global__ __launch_bounds__(256, 4) void k_edge1(
    const float* __restrict__ pos, const int* __restrict__ eidx,
    const float* __restrict__ shf, const int* __restrict__ sorted,
    const float* __restrict__ W1, const float* __restrict__ W2,
    const float* __restrict__ W3,
    const float* __restrict__ sUp1,
    float* __restrict__ agS1, float* __restrict__ agV1)
{
    const int tid = threadIdx.x;
    const int lane = tid & 63;
    const int mu = rfl(tid >> 6);
    const int e0 = blockIdx.x * 64;
    __shared__ float fsh[64][9];
    __shared__ float ysh[64][3];
    __shared__ int ssh[64], rsh[64];
    __shared__ float h1sh[64][65];
    __shared__ float h2sh[64][65];

    if (tid < 64) {
        int sid = sorted[e0 + tid];
        int snd, rcv; float f[8], y[3];
        edge_geom(sid, pos, eidx, shf, &snd, &rcv, f, y);
        ssh[tid] = snd; rsh[tid] = rcv;
        #pragma unroll
        for (int k = 0; k < 8; ++k) fsh[tid][k] = f[k];
        #pragma unroll
        for (int i = 0; i < 3; ++i) ysh[tid][i] = y[i];
    }
    __syncthreads();

    // per-lane preload of edge scalars (lane = edge) for readlane extraction
    const int rAll = rsh[lane];
    const int sAll = ssh[lane];
    const float y0A = ysh[lane][0], y1A = ysh[lane][1], y2A = ysh[lane][2];

    // ---- A1: layer1 (8->64), wave mu computes outs [16mu,+16) ----
    {
        float f[8];
        #pragma unroll
        for (int k = 0; k < 8; ++k) f[k] = fsh[lane][k];
        const float* __restrict__ w1b = W1 + mu * 16;
        #pragma unroll
        for (int j = 0; j < 16; ++j) {
            float a = 0.f;
            #pragma unroll
            for (int k = 0; k < 8; ++k) a = fmaf(f[k], w1b[k * 64 + j], a);
            h1sh[lane][mu * 16 + j] = silu(a);
        }
    }
    __syncthreads();

    // ---- A2: layer2 (64->64), float2 weights ----
    {
        const float2* __restrict__ w2b = (const float2*)W2 + mu * 8;
        float2 acc[8];
        #pragma unroll
        for (int j = 0; j < 8; ++j) acc[j] = make_float2(0.f, 0.f);
        for (int k = 0; k < 64; ++k) {
            float h = h1sh[lane][k];
            const float2* __restrict__ wk = w2b + k * 32;
            #pragma unroll
            for (int j = 0; j < 8; ++j) {
                float2 w = wk[j];
                acc[j].x = fmaf(h, w.x, acc[j].x);
                acc[j].y = fmaf(h, w.y, acc[j].y);
            }
        }
        #pragma unroll
        for (int j = 0; j < 8; ++j) {
            h2sh[lane][mu * 16 + 2 * j]     = silu(acc[j].x);
            h2sh[lane][mu * 16 + 2 * j + 1] = silu(acc[j].y);
        }
    }
    __syncthreads();

    // ---- B: outs [hh*32,+32) of slice m ----
    const int m = mu & 1, hh = mu >> 1;
    float2 t2[16];
    #pragma unroll
    for (int j = 0; j < 16; ++j) t2[j] = make_float2(0.f, 0.f);
    {
        const float2* __restrict__ w3b = (const float2*)W3 + m * 32 + hh * 16;
        for (int k = 0; k < 64; ++k) {
            float h = h2sh[lane][k];
            const float2* __restrict__ wk = w3b + k * 64;
            #pragma unroll
            for (int j = 0; j < 16; ++j) {
                float2 w = wk[j];
                t2[j].x = fmaf(h, w.x, t2[j].x);
                t2[j].y = fmaf(h, w.y, t2[j].y);
            }
        }
    }
    __syncthreads();   // all B-compute done: h1sh/h2sh now dead

    // ---- full transpose: element (e,o) at tr[e][(o+e)&63] ----
    float (*trS)[64] = (float (*)[64])h1sh;
    float (*trV)[64] = (float (*)[64])h2sh;
    float (*tr)[64] = (m == 0) ? trS : trV;
    #pragma unroll
    for (int j = 0; j < 16; ++j) {
        int o0 = hh * 32 + 2 * j;
        tr[lane][(o0 + lane) & 63]     = t2[j].x;
        tr[lane][(o0 + 1 + lane) & 63] = t2[j].y;
    }
    __syncthreads();   // both column-halves present

    // ---- 2-pass aggregation: wave (m,hh) owns edges [hh*32,+32) ----
    float accS = 0.f, a0 = 0.f, a1 = 0.f, a2 = 0.f;
    const int base = hh * 32;
    int cur = rl_i(rAll, base);
    #pragma unroll
    for (int q = 0; q < 4; ++q) {
        // pass 1: branch-free, 8 gathers in flight
        float msg[8];
        #pragma unroll
        for (int i = 0; i < 8; ++i) {
            int e = base + q * 8 + i;
            int sn = rl_i(sAll, e);
            msg[i] = tr[e][(lane + e) & 63] * sUp1[sn * 64 + lane];
        }
        // pass 2: serial run-length over registers only
        #pragma unroll
        for (int i = 0; i < 8; ++i) {
            int e = base + q * 8 + i;
            int rcv = rl_i(rAll, e);
            if (rcv != cur) {
                if (m == 0) {
                    unsafeAtomicAdd(&agS1[cur * 64 + lane], accS); accS = 0.f;
                } else {
                    unsafeAtomicAdd(&agV1[cur * 192 +       lane], a0);
                    unsafeAtomicAdd(&agV1[cur * 192 +  64 + lane], a1);
                    unsafeAtomicAdd(&agV1[cur * 192 + 128 + lane], a2);
                    a0 = a1 = a2 = 0.f;
                }
                cur = rcv;
            }
            if (m == 0) {
                accS += msg[i];
            } else {
                a0 += msg[i] * rl_f(y0A, e);
                a1 += msg[i] * rl_f(y1A, e);
                a2 += msg[i] * rl_f(y2A, e);
            }
        }
    }
    if (m == 0) {
        unsafeAtomicAdd(&agS1[cur * 64 + lane], accS);
    } else {
        unsafeAtomicAdd(&agV1[cur * 192 +       lane], a0);
        unsafeAtomicAdd(&agV1[cur * 192 +  64 + lane], a1);
        unsafeAtomicAdd(&agV1[cur * 192 + 128 + lane], a2);
    }
}

// ---------------- node mid ----------------
__global__ __launch_bounds__(256) void k_node_mid(
    const float* __restrict__ attrs, const float* __restrict__ Wemb,
    const float* __restrict__ K1s, const float* __restrict__ L1s,
    const float* __restrict__ L1v,
    const float* __restrict__ U2s, const float* __restrict__ U2v,
    const float* __restrict__ K2s, const float* __restrict__ K2v,
    const float* __restrict__ agS1, const float* __restrict__ agV1,
    float* __restrict__ sUp2, float* __restrict__ vUp2,
    float* __restrict__ skS2, float* __restrict__ skV2)
{
    int lane = threadIdx.x & 63, wv = threadIdx.x >> 6;
    int n = blockIdx.x * 4 + wv;
    __shared__ float aSsh[4][64];
    __shared__ float aVsh[4][3][64];
    __shared__ float s0sh[4][64];
    __shared__ float s1sh[4][64];
    __shared__ float v1sh[4][3][64];

    int sp = 0;
    #pragma unroll
    for (int v = 0; v < NELEM; ++v) if (attrs[n * NELEM + v] > 0.5f) sp = v;
    aSsh[wv][lane] = agS1[n * 64 + lane];
    #pragma unroll
    for (int i = 0; i < 3; ++i) aVsh[wv][i][lane] = agV1[n * 192 + i * 64 + lane];
    s0sh[wv][lane] = Wemb[sp * 64 + lane];
    __syncthreads();

    float s1 = 0.f;
    #pragma unroll 8
    for (int k = 0; k < 64; ++k) s1 += aSsh[wv][k] * L1s[k * 64 + lane];
    #pragma unroll 8
    for (int k = 0; k < 64; ++k) s1 += s0sh[wv][k] * K1s[(k * NELEM + sp) * 64 + lane];
    float v1[3] = {0.f, 0.f, 0.f};
    #pragma unroll 8
    for (int k = 0; k < 64; ++k) {
        float w = L1v[k * 64 + lane];
        v1[0] += aVsh[wv][0][k] * w;
        v1[1] += aVsh[wv][1][k] * w;
        v1[2] += aVsh[wv][2][k] * w;
    }
    s1sh[wv][lane] = s1;
    #pragma unroll
    for (int i = 0; i < 3; ++i) v1sh[wv][i][lane] = v1[i];
    __syncthreads();

    float su = 0.f, ks = 0.f;
    float vu[3] = {0.f, 0.f, 0.f}, kv[3] = {0.f, 0.f, 0.f};
    #pragma unroll 8
    for (int k = 0; k < 64; ++k) su += s1sh[wv][k] * U2s[k * 64 + lane];
    #pragma unroll 8
    for (int k = 0; k < 64; ++k) ks += s1sh[wv][k] * K2s[(k * NELEM + sp) * 64 + lane];
    #pragma unroll 8
    for (int k = 0; k < 64; ++k) {
        float w = U2v[k * 64 + lane];
        vu[0] += v1sh[wv][0][k] * w;
        vu[1] += v1sh[wv][1][k] * w;
        vu[2] += v1sh[wv][2][k] * w;
    }
    #pragma unroll 8
    for (int k = 0; k < 64; ++k) {
        float w = K2v[(k * NELEM + sp) * 64 + lane];
        kv[0] += v1sh[wv][0][k] * w;
        kv[1] += v1sh[wv][1][k] * w;
        kv[2] += v1sh[wv][2][k] * w;
    }
    sUp2[n * 64 + lane] = su;
    skS2[n * 64 + lane] = ks;
    #pragma unroll
    for (int i = 0; i < 3; ++i) {
        vUp2[n * 192 + i * 64 + lane] = vu[i];
        skV2[n * 192 + i * 64 + lane] = kv[i];
    }
}

// ---------------- edge block 2 ----------------
// 64 edges/block, 4 waves. wave mu: full tpw slice mu (64 outs), lane=edge.
__global__ __launch_bounds__(256, 4) void k_edge2(
    const float* __restrict__ pos, const int* __restrict__ eidx,
    const float* __restrict__ shf, const int* __restrict__ sorted,
    const float* __restrict__ W1, const float* __restrict__ W2,
    const float* __restrict__ W3,
    const float* __restrict__ sUp2, const float* __restrict__ vUp2,
    float* __restrict__ agS2, float* __restrict__ agV2)
{
    const int tid = threadIdx.x;
    const int lane = tid & 63;
    const int mu = rfl(tid >> 6);
    const int e0 = blockIdx.x * 64;
    __shared__ float fsh[64][9];
    __shared__ float ysh[64][3];
    __shared__ int ssh[64], rsh[64];
    __shared__ float h1sh[64][65];
    __shared__ float h2sh[64][65];

    if (tid < 64) {
        int sid = sorted[e0 + tid];
        int snd, rcv; float f[8], y[3];
        edge_geom(sid, pos, eidx, shf, &snd, &rcv, f, y);
        ssh[tid] = snd; rsh[tid] = rcv;
        #pragma unroll
        for (int k = 0; k < 8; ++k) fsh[tid][k] = f[k];
        #pragma unroll
        for (int i = 0; i < 3; ++i) ysh[tid][i] = y[i];
    }
    __syncthreads();

    // per-lane preload of edge scalars (lane = edge) for readlane extraction
    const int rAll = rsh[lane];
    const int sAll = ssh[lane];
    const float y0A = ysh[lane][0], y1A = ysh[lane][1], y2A = ysh[lane][2];

    // ---- A1: layer1 (8->64) ----
    {
        float f[8];
        #pragma unroll
        for (int k = 0; k < 8; ++k) f[k] = fsh[lane][k];
        const float* __restrict__ w1b = W1 + mu * 16;
        #pragma unroll
        for (int j = 0; j < 16; ++j) {
            float a = 0.f;
            #pragma unroll
            for (int k = 0; k < 8; ++k) a = fmaf(f[k], w1b[k * 64 + j], a);
            h1sh[lane][mu * 16 + j] = silu(a);
        }
    }
    __syncthreads();

    // ---- A2: layer2 (64->64), float2 weights ----
    {
        const float2* __restrict__ w2b = (const float2*)W2 + mu * 8;
        float2 acc[8];
        #pragma unroll
        for (int j = 0; j < 8; ++j) acc[j] = make_float2(0.f, 0.f);
        for (int k = 0; k < 64; ++k) {
            float h = h1sh[lane][k];
            const float2* __restrict__ wk = w2b + k * 32;
            #pragma unroll
            for (int j = 0; j < 8; ++j) {
                float2 w = wk[j];
                acc[j].x = fmaf(h, w.x, acc[j].x);
                acc[j].y = fmaf(h, w.y, acc[j].y);
            }
        }
        #pragma unroll
        for (int j = 0; j < 8; ++j) {
            h2sh[lane][mu * 16 + 2 * j]     = silu(acc[j].x);
            h2sh[lane][mu * 16 + 2 * j + 1] = silu(acc[j].y);
        }
    }
    __syncthreads();   // last block-wide barrier: h1sh free after this

    // ---- B: layer3 slice mu: 64 outs as float2 ----
    float2 t2[32];
    #pragma unroll
    for (int j = 0; j < 32; ++j) t2[j] = make_float2(0.f, 0.f);
    {
        const float2* __restrict__ w3b = (const float2*)W3 + mu * 32;
        for (int k = 0; k < 64; ++k) {
            float h = h2sh[lane][k];
            const float2* __restrict__ wk = w3b + k * 128;
            #pragma unroll
            for (int j = 0; j < 32; ++j) {
                float2 w = wk[j];
                t2[j].x = fmaf(h, w.x, t2[j].x);
                t2[j].y = fmaf(h, w.y, t2[j].y);
            }
        }
    }

    // ---- wave-local chunked transpose + 2-pass aggregation ----
    float (*tr)[64] = (float (*)[64])((float*)h1sh + (size_t)mu * 1024);
    float accS = 0.f, a0 = 0.f, a1 = 0.f, a2 = 0.f;
    int cur = rl_i(rAll, 0);
    int curC[3] = {cur, cur, cur};
    float accC[3] = {0.f, 0.f, 0.f};
    for (int c = 0; c < 4; ++c) {
        if ((lane >> 4) == c) {
            int li = lane & 15;
            #pragma unroll
            for (int j = 0; j < 32; ++j) {
                tr[li][(2 * j + li) & 63]     = t2[j].x;
                tr[li][(2 * j + 1 + li) & 63] = t2[j].y;
            }
        }
        // no barrier: same-wave DS ops are in order
        if (mu == 2) {
            // mC = tpw2 * v_e : three component-sequential 2-pass sweeps
            #pragma unroll
            for (int comp = 0; comp < 3; ++comp) {
                #pragma unroll
                for (int h = 0; h < 2; ++h) {
                    float msg[8];
                    #pragma unroll
                    for (int i = 0; i < 8; ++i) {
                        int li = h * 8 + i;
                        int sn = rl_i(sAll, c * 16 + li);
                        msg[i] = tr[li][(lane + li) & 63]
                               * vUp2[sn * 192 + comp * 64 + lane];
                    }
                    #pragma unroll
                    for (int i = 0; i < 8; ++i) {
                        int e = c * 16 + h * 8 + i;
                        int rcv = rl_i(rAll, e);
                        if (rcv != curC[comp]) {
                            unsafeAtomicAdd(&agV2[curC[comp] * 384 + comp * 128 + 64 + lane],
                                            accC[comp]);
                            accC[comp] = 0.f;
                            curC[comp] = rcv;
                        }
                        accC[comp] += msg[i];
                    }
                }
            }
        } else {
            #pragma unroll
            for (int h = 0; h < 2; ++h) {
                // pass 1: branch-free gathers
                float msg[8];
                #pragma unroll
                for (int i = 0; i < 8; ++i) {
                    int li = h * 8 + i;
                    int e = c * 16 + li;
                    int sn = rl_i(sAll, e);
                    float tv = tr[li][(lane + li) & 63];
                    if (mu <= 1) {
                        msg[i] = tv * sUp2[sn * 64 + lane];
                    } else {  // mu == 3: contract v_e . Y1 at load time
                        float g0 = vUp2[sn * 192 +       lane];
                        float g1 = vUp2[sn * 192 +  64 + lane];
                        float g2 = vUp2[sn * 192 + 128 + lane];
                        msg[i] = tv * (g0 * rl_f(y0A, e) + g1 * rl_f(y1A, e)
                                     + g2 * rl_f(y2A, e)) * 0.577350269189626f;
                    }
                }
                // pass 2: serial run-length over registers
                #pragma unroll
                for (int i = 0; i < 8; ++i) {
                    int e = c * 16 + h * 8 + i;
                    int rcv = rl_i(rAll, e);
                    if (rcv != cur) {
                        if (mu == 0) {
                            unsafeAtomicAdd(&agS2[cur * 128 + lane], accS); accS = 0.f;
                        } else if (mu == 1) {
                            unsafeAtomicAdd(&agV2[cur * 384 + 0 * 128 + lane], a0);
                            unsafeAtomicAdd(&agV2[cur * 384 + 1 * 128 + lane], a1);
                            unsafeAtomicAdd(&agV2[cur * 384 + 2 * 128 + lane], a2);
                            a0 = a1 = a2 = 0.f;
                        } else {  // mu == 3
                            unsafeAtomicAdd(&agS2[cur * 128 + 64 + lane], accS); accS = 0.f;
                        }
                        cur = rcv;
                    }
                    if (mu == 0 || mu == 3) {
                        accS += msg[i];
                    } else {  // mu == 1
                        a0 += msg[i] * rl_f(y0A, e);
                        a1 += msg[i] * rl_f(y1A, e);
                        a2 += msg[i] * rl_f(y2A, e);
                    }
                }
            }
        }
    }
    if (mu == 0) {
        unsafeAtomicAdd(&agS2[cur * 128 + lane], accS);
    } else if (mu == 1) {
        unsafeAtomicAdd(&agV2[cur * 384 + 0 * 128 + lane], a0);
        unsafeAtomicAdd(&agV2[cur * 384 + 1 * 128 + lane], a1);
        unsafeAtomicAdd(&agV2[cur * 384 + 2 * 128 + lane], a2);
    } else if (mu == 2) {
        #pragma unroll
        for (int comp = 0; comp < 3; ++comp)
            unsafeAtomicAdd(&agV2[curC[comp] * 384 + comp * 128 + 64 + lane], accC[comp]);
    } else {
        unsafeAtomicAdd(&agS2[cur * 128 + 64 + lane], accS);
    }
}

// ---------------- node out ----------------
__global__ __launch_bounds__(256) void k_node_out(
    const float* __restrict__ L2s, const float* __restrict__ L2v,
    const float* __restrict__ agS2, const float* __restrict__ agV2,
    const float* __restrict__ skS2, const float* __restrict__ skV2,
    float* __restrict__ out)
{
    int lane = threadIdx.x & 63, wv = threadIdx.x >> 6;
    int n = blockIdx.x * 4 + wv;
    __shared__ __align__(16) float aS[4][128];
    __shared__ __align__(16) float aV[4][3][128];

    aS[wv][lane]      = agS2[n * 128 + lane];
    aS[wv][64 + lane] = agS2[n * 128 + 64 + lane];
    #pragma unroll
    for (int i = 0; i < 3; ++i) {
        aV[wv][i][lane]      = agV2[n * 384 + i * 128 + lane];
        aV[wv][i][64 + lane] = agV2[n * 384 + i * 128 + 64 + lane];
    }
    __syncthreads();

    float s2 = skS2[n * 64 + lane];
    #pragma unroll 8
    for (int u = 0; u < 128; ++u) s2 += aS[wv][u] * L2s[u * 64 + lane];
    float v2[3];
    #pragma unroll
    for (int i = 0; i < 3; ++i) v2[i] = skV2[n * 192 + i * 64 + lane];
    #pragma unroll 8
    for (int u = 0; u < 128; ++u) {
        float w = L2v[u * 64 + lane];
        v2[0] += aV[wv][0][u] * w;
        v2[1] += aV[wv][1][u] * w;
        v2[2] += aV[wv][2][u] * w;
    }
    out[(size_t)n * 256 + lane] = s2;
    #pragma unroll
    for (int i = 0; i < 3; ++i)
        out[(size_t)n * 256 + 64 + lane * 3 + i] = v2[i];
}

// ---------------- host launcher ----------------
extern "C" void kernel_launch(void* const* d_in, const int* in_sizes, int n_in,
                              void* d_out, int out_size, void* d_ws, size_t ws_size,
                              hipStream_t stream)
{
    (void)in_sizes; (void)n_in; (void)out_size; (void)ws_size;
    const float* positions  = (const float*)d_in[0];
    const float* node_attrs = (const float*)d_in[1];
    const int*   edge_index = (const int*)d_in[2];
    const float* shifts     = (const float*)d_in[3];
    const float* W_embed    = (const float*)d_in[4];
    const float* R1W1 = (const float*)d_in[5];
    const float* R1W2 = (const float*)d_in[6];
    const float* R1W3 = (const float*)d_in[7];
    const float* U1s  = (const float*)d_in[8];
    const float* L1s  = (const float*)d_in[9];
    const float* L1v  = (const float*)d_in[10];
    const float* K1s  = (const float*)d_in[11];
    const float* R2W1 = (const float*)d_in[12];
    const float* R2W2 = (const float*)d_in[13];
    const float* R2W3 = (const float*)d_in[14];
    const float* U2s  = (const float*)d_in[15];
    const float* U2v  = (const float*)d_in[16];
    const float* L2s  = (const float*)d_in[17];
    const float* L2v  = (const float*)d_in[18];
    const float* K2s  = (const float*)d_in[19];
    const float* K2v  = (const float*)d_in[20];

    float* wsf = (float*)d_ws;
    int*   wsi = (int*)(wsf + OFF_INT);
    int* hist   = wsi;
    int* cursor = wsi + 20000;
    int* sorted = wsi + 40000;

    // phase-1 accumulators (AGS1+AGV1 = 4NC) and histogram
    hipMemsetAsync(wsf + OFF_AGS1, 0, (size_t)4 * NC * sizeof(float), stream);
    hipMemsetAsync(hist, 0, 20000 * sizeof(int), stream);

    k_hist<<<NEDGES / 256, 256, 0, stream>>>(edge_index, hist);
    k_scan<<<1, 1024, 0, stream>>>(hist, cursor);
    k_scatter<<<NEDGES / 256, 256, 0, stream>>>(edge_index, cursor, sorted);

    k_node_pre<<<NNODES / 4, 256, 0, stream>>>(node_attrs, W_embed, U1s, wsf + OFF_SUP1);
    k_edge1<<<NEDGES / 64, 256, 0, stream>>>(positions, edge_index, shifts, sorted,
                                             R1W1, R1W2, R1W3,
                                             wsf + OFF_SUP1, wsf + OFF_AGS1, wsf + OFF_AGV1);
    k_node_mid<<<NNODES / 4, 256, 0, stream>>>(node_attrs, W_embed, K1s, L1s, L1v,
                                               U2s, U2v, K2s, K2v,
                                               wsf + OFF_AGS1, wsf + OFF_AGV1,
                                               wsf + OFF_SUP2, wsf + OFF_VUP2,
                                               wsf + OFF_SKS2, wsf + OFF_SKV2);
    // phase-2 accumulators (AGS2+AGV2 = 8NC, overlaid on phase-1 region)
    hipMemsetAsync(wsf + OFF_AGS2, 0, (size_t)8 * NC * sizeof(float), stream);
    k_edge2<<<NEDGES / 64, 256, 0, stream>>>(positions, edge_index, shifts, sorted,
                                             R2W1, R2W2, R2W3,
                                             wsf + OFF_SUP2, wsf + OFF_VUP2,
                                             wsf + OFF_AGS2, wsf + OFF_AGV2);
    k_node_out<<<NNODES / 4, 256, 0, stream>>>(L2s, L2v, wsf + OFF_AGS2, wsf + OFF_AGV2,
                                               wsf + OFF_SKS2, wsf + OFF_SKV2,
                                               (float*)d_out);
}

// Round 10
// 722.833 us; speedup vs baseline: 1.0855x; 1.0855x over previous
//
#include <hip/hip_runtime.h>

// ---------------- problem constants ----------------
#define NNODES 20000
#define NEDGES 320000
#define NELEM  10
#define NC     (NNODES * 64)   // 1,280,000

// ---------------- phase-overlaid ws layout (float offsets) ----------------
#define OFF_SUP1 ((size_t)0)
#define OFF_AGS1 ((size_t)1 * NC)
#define OFF_AGV1 ((size_t)2 * NC)
#define OFF_AGS2 ((size_t)0)
#define OFF_AGV2 ((size_t)2 * NC)
#define OFF_SUP2 ((size_t)8 * NC)
#define OFF_VUP2 ((size_t)9 * NC)
#define OFF_SKS2 ((size_t)12 * NC)
#define OFF_SKV2 ((size_t)13 * NC)
#define OFF_INT  ((size_t)16 * NC)
// bf16 split weights (ushort units) after the 360000 ints:
//   w3a_hi [128][64] @0, w3a_lo @8192, w3b_hi [256][64] @16384, w3b_lo @32768

typedef __attribute__((ext_vector_type(8))) short bf16x8;
typedef __attribute__((ext_vector_type(4))) float f32x4;

__device__ __forceinline__ float silu(float x) { return x / (1.0f + __expf(-x)); }
__device__ __forceinline__ int rfl(int v) { return __builtin_amdgcn_readfirstlane(v); }
__device__ __forceinline__ int rl_i(int v, int l) { return __builtin_amdgcn_readlane(v, l); }
__device__ __forceinline__ float rl_f(float v, int l) {
    return __int_as_float(__builtin_amdgcn_readlane(__float_as_int(v), l));
}
// split two f32 into packed bf16 hi-pair (x) and lo-pair (y), round-to-nearest
__device__ __forceinline__ uint2 split2(float x0, float x1) {
    unsigned int b0 = __float_as_uint(x0), b1 = __float_as_uint(x1);
    unsigned int h0 = (b0 + 0x7FFF + ((b0 >> 16) & 1)) & 0xFFFF0000u;
    unsigned int h1 = (b1 + 0x7FFF + ((b1 >> 16) & 1)) & 0xFFFF0000u;
    unsigned int l0 = __float_as_uint(x0 - __uint_as_float(h0));
    unsigned int l1 = __float_as_uint(x1 - __uint_as_float(h1));
    unsigned int hi = (h0 >> 16) | (h1 & 0xFFFF0000u);
    unsigned int lo = ((l0 + 0x7FFF + ((l0 >> 16) & 1)) >> 16)
                    | ((l1 + 0x7FFF + ((l1 >> 16) & 1)) & 0xFFFF0000u);
    return make_uint2(hi, lo);
}

// ---------------- weight split: W3 -> transposed bf16 hi/lo ----------------
__global__ __launch_bounds__(256) void k_wsplit(
    const float* __restrict__ W3a, const float* __restrict__ W3b,
    unsigned short* __restrict__ out)
{
    int t = blockIdx.x * 256 + threadIdx.x;   // 24576 total
    float x; unsigned short *ph, *pl; int idx;
    if (t < 8192) {
        int n = t >> 6, k = t & 63;
        x = W3a[k * 128 + n]; ph = out; pl = out + 8192; idx = n * 64 + k;
    } else {
        int u = t - 8192; int n = u >> 6, k = u & 63;
        x = W3b[k * 256 + n]; ph = out + 16384; pl = out + 32768; idx = n * 64 + k;
    }
    unsigned int b = __float_as_uint(x);
    unsigned int h = (b + 0x7FFF + ((b >> 16) & 1)) & 0xFFFF0000u;
    unsigned int r = __float_as_uint(x - __uint_as_float(h));
    ph[idx] = (unsigned short)(h >> 16);
    pl[idx] = (unsigned short)((r + 0x7FFF + ((r >> 16) & 1)) >> 16);
}

// ---------------- sort by rcv ----------------
__global__ __launch_bounds__(256) void k_hist(const int* __restrict__ eidx,
                                              int* __restrict__ hist)
{
    int e = blockIdx.x * 256 + threadIdx.x;
    atomicAdd(&hist[eidx[NEDGES + e]], 1);
}

__global__ __launch_bounds__(1024) void k_scan(const int* __restrict__ hist,
                                               int* __restrict__ cursor)
{
    __shared__ int wsum[16];
    __shared__ int gbase;
    int tid = threadIdx.x;
    int lane = tid & 63, wvid = tid >> 6;
    if (tid == 0) gbase = 0;
    __syncthreads();
    for (int seg = 0; seg < 20; ++seg) {
        int i = seg * 1024 + tid;
        int v = (i < NNODES) ? hist[i] : 0;
        int s = v;
        #pragma unroll
        for (int d = 1; d < 64; d <<= 1) {
            int t = __shfl_up(s, d, 64);
            if (lane >= d) s += t;
        }
        if (lane == 63) wsum[wvid] = s;
        __syncthreads();
        if (wvid == 0) {
            int w = (lane < 16) ? wsum[lane] : 0;
            #pragma unroll
            for (int d = 1; d < 16; d <<= 1) {
                int t = __shfl_up(w, d, 64);
                if (lane >= d) w += t;
            }
            if (lane < 16) wsum[lane] = w;
        }
        __syncthreads();
        int wbase = (wvid == 0) ? 0 : wsum[wvid - 1];
        if (i < NNODES) cursor[i] = gbase + wbase + s - v;
        int segtot = wsum[15];
        __syncthreads();
        if (tid == 0) gbase += segtot;
    }
}

__global__ __launch_bounds__(256) void k_scatter(const int* __restrict__ eidx,
                                                 int* __restrict__ cursor,
                                                 int* __restrict__ sorted)
{
    int e = blockIdx.x * 256 + threadIdx.x;
    int pos = atomicAdd(&cursor[eidx[NEDGES + e]], 1);
    sorted[pos] = e;
}

// ---------------- edge geometry helper ----------------
__device__ __forceinline__ void edge_geom(
    int e, const float* __restrict__ pos, const int* __restrict__ eidx,
    const float* __restrict__ shf, int* snd_out, int* rcv_out,
    float feats[8], float y[3])
{
    int snd = eidx[e], rcv = eidx[NEDGES + e];
    *snd_out = snd; *rcv_out = rcv;
    float dx = pos[snd * 3 + 0] - pos[rcv * 3 + 0] + shf[(size_t)e * 3 + 0];
    float dy = pos[snd * 3 + 1] - pos[rcv * 3 + 1] + shf[(size_t)e * 3 + 1];
    float dz = pos[snd * 3 + 2] - pos[rcv * 3 + 2] + shf[(size_t)e * 3 + 2];
    float len = sqrtf(dx * dx + dy * dy + dz * dz + 1e-12f);
    float inv = 1.0f / len;
    float u = len * 0.2f;
    float u2 = u * u, u4 = u2 * u2, u5 = u4 * u, u6 = u5 * u, u7 = u6 * u;
    float cut = (u < 1.0f) ? (1.0f - 21.0f * u5 + 35.0f * u6 - 15.0f * u7) : 0.0f;
    float s = 0.632455532033676f * inv * cut;
    #pragma unroll
    for (int k = 0; k < 8; ++k)
        feats[k] = s * sinf((float)(k + 1) * 0.628318530717959f * len);
    y[0] = 1.73205080756888f * dx * inv;
    y[1] = 1.73205080756888f * dy * inv;
    y[2] = 1.73205080756888f * dz * inv;
}

// ---------------- node pre ----------------
__global__ __launch_bounds__(256) void k_node_pre(
    const float* __restrict__ attrs, const float* __restrict__ Wemb,
    const float* __restrict__ U1s, float* __restrict__ sUp1)
{
    int lane = threadIdx.x & 63, wv = threadIdx.x >> 6;
    int n = blockIdx.x * 4 + wv;
    __shared__ __align__(16) float s0sh[4][64];
    float s0 = 0.f;
    #pragma unroll
    for (int v = 0; v < NELEM; ++v) s0 += attrs[n * NELEM + v] * Wemb[v * 64 + lane];
    s0sh[wv][lane] = s0;
    __syncthreads();
    float a = 0.f;
    #pragma unroll 8
    for (int k = 0; k < 64; ++k) a += s0sh[wv][k] * U1s[k * 64 + lane];
    sUp1[n * 64 + lane] = a;
}

// ---------------- edge block 1 (B-phase on MFMA, split-bf16) ----------------
__global__ __launch_bounds__(256) void k_edge1(
    const float* __restrict__ pos, const int* __restrict__ eidx,
    const float* __restrict__ shf, const int* __restrict__ sorted,
    const float* __restrict__ W1, const float* __restrict__ W2,
    const unsigned short* __restrict__ w3h, const unsigned short* __restrict__ w3l,
    const float* __restrict__ sUp1,
    float* __restrict__ agS1, float* __restrict__ agV1)
{
    const int tid = threadIdx.x;
    const int lane = tid & 63;
    const int mu = rfl(tid >> 6);
    const int e0 = blockIdx.x * 64;
    __shared__ float fsh[64][9];
    __shared__ float ysh[64][3];
    __shared__ int ssh[64], rsh[64];
    __shared__ __align__(16) float h1sh[64][65];
    __shared__ __align__(16) unsigned short h2buf[2][64][72];   // hi, lo

    if (tid < 64) {
        int sid = sorted[e0 + tid];
        int snd, rcv; float f[8], y[3];
        edge_geom(sid, pos, eidx, shf, &snd, &rcv, f, y);
        ssh[tid] = snd; rsh[tid] = rcv;
        #pragma unroll
        for (int k = 0; k < 8; ++k) fsh[tid][k] = f[k];
        #pragma unroll
        for (int i = 0; i < 3; ++i) ysh[tid][i] = y[i];
    }
    __syncthreads();

    const int rAll = rsh[lane];
    const int sAll = ssh[lane];
    const float y0A = ysh[lane][0], y1A = ysh[lane][1], y2A = ysh[lane][2];

    // ---- A1: 8->64 ----
    {
        float f[8];
        #pragma unroll
        for (int k = 0; k < 8; ++k) f[k] = fsh[lane][k];
        const float* __restrict__ w1b = W1 + mu * 16;
        #pragma unroll
        for (int j = 0; j < 16; ++j) {
            float a = 0.f;
            #pragma unroll
            for (int k = 0; k < 8; ++k) a = fmaf(f[k], w1b[k * 64 + j], a);
            h1sh[lane][mu * 16 + j] = silu(a);
        }
    }
    __syncthreads();

    // ---- A2: 64->64 (VALU fp32), epilogue split-bf16 into h2buf ----
    {
        const float2* __restrict__ w2b = (const float2*)W2 + mu * 8;
        float2 acc[8];
        #pragma unroll
        for (int j = 0; j < 8; ++j) acc[j] = make_float2(0.f, 0.f);
        for (int k = 0; k < 64; ++k) {
            float h = h1sh[lane][k];
            const float2* __restrict__ wk = w2b + k * 32;
            #pragma unroll
            for (int j = 0; j < 8; ++j) {
                float2 w = wk[j];
                acc[j].x = fmaf(h, w.x, acc[j].x);
                acc[j].y = fmaf(h, w.y, acc[j].y);
            }
        }
        #pragma unroll
        for (int j = 0; j < 8; ++j) {
            uint2 p = split2(silu(acc[j].x), silu(acc[j].y));
            *(unsigned int*)&h2buf[0][lane][mu * 16 + 2 * j] = p.x;
            *(unsigned int*)&h2buf[1][lane][mu * 16 + 2 * j] = p.y;
        }
    }
    __syncthreads();

    // ---- B: MFMA, wave (m,hh) computes outs [hh*32,+32) of slice m ----
    const int m = mu & 1, hh = mu >> 1;
    const int q = lane >> 4, nl = lane & 15;
    f32x4 accT[4][2];
    for (int mt = 0; mt < 4; ++mt) {
        const unsigned short* ar = &h2buf[0][mt * 16 + nl][0];
        const unsigned short* al = &h2buf[1][mt * 16 + nl][0];
        bf16x8 ah0 = *(const bf16x8*)(ar + q * 8);
        bf16x8 ah1 = *(const bf16x8*)(ar + 32 + q * 8);
        bf16x8 al0 = *(const bf16x8*)(al + q * 8);
        bf16x8 al1 = *(const bf16x8*)(al + 32 + q * 8);
        #pragma unroll
        for (int nt = 0; nt < 2; ++nt) {
            int ng = m * 64 + hh * 32 + nt * 16 + nl;
            const unsigned short* wh = w3h + ng * 64 + q * 8;
            const unsigned short* wl = w3l + ng * 64 + q * 8;
            bf16x8 bh0 = *(const bf16x8*)wh;
            bf16x8 bh1 = *(const bf16x8*)(wh + 32);
            bf16x8 bl0 = *(const bf16x8*)wl;
            bf16x8 bl1 = *(const bf16x8*)(wl + 32);
            f32x4 a = {0.f, 0.f, 0.f, 0.f};
            a = __builtin_amdgcn_mfma_f32_16x16x32_bf16(ah0, bh0, a, 0, 0, 0);
            a = __builtin_amdgcn_mfma_f32_16x16x32_bf16(ah1, bh1, a, 0, 0, 0);
            a = __builtin_amdgcn_mfma_f32_16x16x32_bf16(ah0, bl0, a, 0, 0, 0);
            a = __builtin_amdgcn_mfma_f32_16x16x32_bf16(ah1, bl1, a, 0, 0, 0);
            a = __builtin_amdgcn_mfma_f32_16x16x32_bf16(al0, bh0, a, 0, 0, 0);
            a = __builtin_amdgcn_mfma_f32_16x16x32_bf16(al1, bh1, a, 0, 0, 0);
            accT[mt][nt] = a;
        }
    }
    __syncthreads();   // all B done: h1sh/h2buf dead

    // ---- transpose from D layout: D[m=q*4+r][n=lane&15] per tile ----
    float (*trS)[64] = (float (*)[64])h1sh;
    float (*trV)[64] = (float (*)[64])&h2buf[0][0][0];
    float (*tr)[64] = (m == 0) ? trS : trV;
    #pragma unroll
    for (int mt = 0; mt < 4; ++mt)
        #pragma unroll
        for (int nt = 0; nt < 2; ++nt)
            #pragma unroll
            for (int r = 0; r < 4; ++r) {
                int e = mt * 16 + q * 4 + r;
                int o = hh * 32 + nt * 16 + nl;
                tr[e][(o + e) & 63] = accT[mt][nt][r];
            }
    __syncthreads();

    // ---- aggregation: wave (m,hh) owns edges [hh*32,+32) ----
    float accS = 0.f, a0 = 0.f, a1 = 0.f, a2 = 0.f;
    const int base = hh * 32;
    int cur = rl_i(rAll, base);
    #pragma unroll 8
    for (int i = 0; i < 32; ++i) {
        int e = base + i;
        int rcv = rl_i(rAll, e);
        int snd = rl_i(sAll, e);
        float tv = tr[e][(lane + e) & 63];
        if (rcv != cur) {
            if (m == 0) {
                unsafeAtomicAdd(&agS1[cur * 64 + lane], accS); accS = 0.f;
            } else {
                unsafeAtomicAdd(&agV1[cur * 192 +       lane], a0);
                unsafeAtomicAdd(&agV1[cur * 192 +  64 + lane], a1);
                unsafeAtomicAdd(&agV1[cur * 192 + 128 + lane], a2);
                a0 = a1 = a2 = 0.f;
            }
            cur = rcv;
        }
        float msg = tv * sUp1[snd * 64 + lane];
        if (m == 0) {
            accS += msg;
        } else {
            a0 += msg * rl_f(y0A, e);
            a1 += msg * rl_f(y1A, e);
            a2 += msg * rl_f(y2A, e);
        }
    }
    if (m == 0) {
        unsafeAtomicAdd(&agS1[cur * 64 + lane], accS);
    } else {
        unsafeAtomicAdd(&agV1[cur * 192 +       lane], a0);
        unsafeAtomicAdd(&agV1[cur * 192 +  64 + lane], a1);
        unsafeAtomicAdd(&agV1[cur * 192 + 128 + lane], a2);
    }
}

// ---------------- node mid ----------------
__global__ __launch_bounds__(256) void k_node_mid(
    const float* __restrict__ attrs, const float* __restrict__ Wemb,
    const float* __restrict__ K1s, const float* __restrict__ L1s,
    const float* __restrict__ L1v,
    const float* __restrict__ U2s, const float* __restrict__ U2v,
    const float* __restrict__ K2s, const float* __restrict__ K2v,
    const float* __restrict__ agS1, const float* __restrict__ agV1,
    float* __restrict__ sUp2, float* __restrict__ vUp2,
    float* __restrict__ skS2, float* __restrict__ skV2)
{
    int lane = threadIdx.x & 63, wv = threadIdx.x >> 6;
    int n = blockIdx.x * 4 + wv;
    __shared__ float aSsh[4][64];
    __shared__ float aVsh[4][3][64];
    __shared__ float s0sh[4][64];
    __shared__ float s1sh[4][64];
    __shared__ float v1sh[4][3][64];

    int sp = 0;
    #pragma unroll
    for (int v = 0; v < NELEM; ++v) if (attrs[n * NELEM + v] > 0.5f) sp = v;
    aSsh[wv][lane] = agS1[n * 64 + lane];
    #pragma unroll
    for (int i = 0; i < 3; ++i) aVsh[wv][i][lane] = agV1[n * 192 + i * 64 + lane];
    s0sh[wv][lane] = Wemb[sp * 64 + lane];
    __syncthreads();

    float s1 = 0.f;
    #pragma unroll 8
    for (int k = 0; k < 64; ++k) s1 += aSsh[wv][k] * L1s[k * 64 + lane];
    #pragma unroll 8
    for (int k = 0; k < 64; ++k) s1 += s0sh[wv][k] * K1s[(k * NELEM + sp) * 64 + lane];
    float v1[3] = {0.f, 0.f, 0.f};
    #pragma unroll 8
    for (int k = 0; k < 64; ++k) {
        float w = L1v[k * 64 + lane];
        v1[0] += aVsh[wv][0][k] * w;
        v1[1] += aVsh[wv][1][k] * w;
        v1[2] += aVsh[wv][2][k] * w;
    }
    s1sh[wv][lane] = s1;
    #pragma unroll
    for (int i = 0; i < 3; ++i) v1sh[wv][i][lane] = v1[i];
    __syncthreads();

    float su = 0.f, ks = 0.f;
    float vu[3] = {0.f, 0.f, 0.f}, kv[3] = {0.f, 0.f, 0.f};
    #pragma unroll 8
    for (int k = 0; k < 64; ++k) su += s1sh[wv][k] * U2s[k * 64 + lane];
    #pragma unroll 8
    for (int k = 0; k < 64; ++k) ks += s1sh[wv][k] * K2s[(k * NELEM + sp) * 64 + lane];
    #pragma unroll 8
    for (int k = 0; k < 64; ++k) {
        float w = U2v[k * 64 + lane];
        vu[0] += v1sh[wv][0][k] * w;
        vu[1] += v1sh[wv][1][k] * w;
        vu[2] += v1sh[wv][2][k] * w;
    }
    #pragma unroll 8
    for (int k = 0; k < 64; ++k) {
        float w = K2v[(k * NELEM + sp) * 64 + lane];
        kv[0] += v1sh[wv][0][k] * w;
        kv[1] += v1sh[wv][1][k] * w;
        kv[2] += v1sh[wv][2][k] * w;
    }
    sUp2[n * 64 + lane] = su;
    skS2[n * 64 + lane] = ks;
    #pragma unroll
    for (int i = 0; i < 3; ++i) {
        vUp2[n * 192 + i * 64 + lane] = vu[i];
        skV2[n * 192 + i * 64 + lane] = kv[i];
    }
}

// ---------------- edge block 2 (B-phase on MFMA, split-bf16) ----------------
__global__ __launch_bounds__(256) void k_edge2(
    const float* __restrict__ pos, const int* __restrict__ eidx,
    const float* __restrict__ shf, const int* __restrict__ sorted,
    const float* __restrict__ W1, const float* __restrict__ W2,
    const unsigned short* __restrict__ w3h, const unsigned short* __restrict__ w3l,
    const float* __restrict__ sUp2, const float* __restrict__ vUp2,
    float* __restrict__ agS2, float* __restrict__ agV2)
{
    const int tid = threadIdx.x;
    const int lane = tid & 63;
    const int mu = rfl(tid >> 6);
    const int e0 = blockIdx.x * 64;
    __shared__ float fsh[64][9];
    __shared__ float ysh[64][3];
    __shared__ int ssh[64], rsh[64];
    __shared__ __align__(16) float h1sh[64][65];
    __shared__ __align__(16) unsigned short h2buf[2][64][72];

    if (tid < 64) {
        int sid = sorted[e0 + tid];
        int snd, rcv; float f[8], y[3];
        edge_geom(sid, pos, eidx, shf, &snd, &rcv, f, y);
        ssh[tid] = snd; rsh[tid] = rcv;
        #pragma unroll
        for (int k = 0; k < 8; ++k) fsh[tid][k] = f[k];
        #pragma unroll
        for (int i = 0; i < 3; ++i) ysh[tid][i] = y[i];
    }
    __syncthreads();

    const int rAll = rsh[lane];
    const int sAll = ssh[lane];
    const float y0A = ysh[lane][0], y1A = ysh[lane][1], y2A = ysh[lane][2];

    // ---- A1 ----
    {
        float f[8];
        #pragma unroll
        for (int k = 0; k < 8; ++k) f[k] = fsh[lane][k];
        const float* __restrict__ w1b = W1 + mu * 16;
        #pragma unroll
        for (int j = 0; j < 16; ++j) {
            float a = 0.f;
            #pragma unroll
            for (int k = 0; k < 8; ++k) a = fmaf(f[k], w1b[k * 64 + j], a);
            h1sh[lane][mu * 16 + j] = silu(a);
        }
    }
    __syncthreads();

    // ---- A2 with split-bf16 epilogue ----
    {
        const float2* __restrict__ w2b = (const float2*)W2 + mu * 8;
        float2 acc[8];
        #pragma unroll
        for (int j = 0; j < 8; ++j) acc[j] = make_float2(0.f, 0.f);
        for (int k = 0; k < 64; ++k) {
            float h = h1sh[lane][k];
            const float2* __restrict__ wk = w2b + k * 32;
            #pragma unroll
            for (int j = 0; j < 8; ++j) {
                float2 w = wk[j];
                acc[j].x = fmaf(h, w.x, acc[j].x);
                acc[j].y = fmaf(h, w.y, acc[j].y);
            }
        }
        #pragma unroll
        for (int j = 0; j < 8; ++j) {
            uint2 p = split2(silu(acc[j].x), silu(acc[j].y));
            *(unsigned int*)&h2buf[0][lane][mu * 16 + 2 * j] = p.x;
            *(unsigned int*)&h2buf[1][lane][mu * 16 + 2 * j] = p.y;
        }
    }
    __syncthreads();   // last block-wide barrier: h1sh free after this

    // ---- B-MFMA per m-tile, fold in transpose + aggregation (wave-local) ----
    const int q = lane >> 4, nl = lane & 15;
    float (*tr)[64] = (float (*)[64])((float*)h1sh + (size_t)mu * 1024);
    float accS = 0.f, a0 = 0.f, a1 = 0.f, a2 = 0.f;
    int cur = rl_i(rAll, 0);
    for (int mt = 0; mt < 4; ++mt) {
        const unsigned short* ar = &h2buf[0][mt * 16 + nl][0];
        const unsigned short* al = &h2buf[1][mt * 16 + nl][0];
        bf16x8 ah0 = *(const bf16x8*)(ar + q * 8);
        bf16x8 ah1 = *(const bf16x8*)(ar + 32 + q * 8);
        bf16x8 al0 = *(const bf16x8*)(al + q * 8);
        bf16x8 al1 = *(const bf16x8*)(al + 32 + q * 8);
        #pragma unroll
        for (int nt = 0; nt < 4; ++nt) {
            int ng = mu * 64 + nt * 16 + nl;
            const unsigned short* wh = w3h + ng * 64 + q * 8;
            const unsigned short* wl = w3l + ng * 64 + q * 8;
            bf16x8 bh0 = *(const bf16x8*)wh;
            bf16x8 bh1 = *(const bf16x8*)(wh + 32);
            bf16x8 bl0 = *(const bf16x8*)wl;
            bf16x8 bl1 = *(const bf16x8*)(wl + 32);
            f32x4 a = {0.f, 0.f, 0.f, 0.f};
            a = __builtin_amdgcn_mfma_f32_16x16x32_bf16(ah0, bh0, a, 0, 0, 0);
            a = __builtin_amdgcn_mfma_f32_16x16x32_bf16(ah1, bh1, a, 0, 0, 0);
            a = __builtin_amdgcn_mfma_f32_16x16x32_bf16(ah0, bl0, a, 0, 0, 0);
            a = __builtin_amdgcn_mfma_f32_16x16x32_bf16(ah1, bl1, a, 0, 0, 0);
            a = __builtin_amdgcn_mfma_f32_16x16x32_bf16(al0, bh0, a, 0, 0, 0);
            a = __builtin_amdgcn_mfma_f32_16x16x32_bf16(al1, bh1, a, 0, 0, 0);
            #pragma unroll
            for (int r = 0; r < 4; ++r) {
                int li = q * 4 + r;
                tr[li][(nt * 16 + nl + li) & 63] = a[r];
            }
        }
        // aggregation chunk mt (same-wave DS ordering: tr write -> read)
        #pragma unroll 4
        for (int i = 0; i < 16; ++i) {
            int e = mt * 16 + i;
            int rcv = rl_i(rAll, e);
            int snd = rl_i(sAll, e);
            float tv = tr[i][(lane + i) & 63];
            if (rcv != cur) {
                if (mu == 0) {
                    unsafeAtomicAdd(&agS2[cur * 128 + lane], accS); accS = 0.f;
                } else if (mu == 1) {
                    unsafeAtomicAdd(&agV2[cur * 384 + 0 * 128 + lane], a0);
                    unsafeAtomicAdd(&agV2[cur * 384 + 1 * 128 + lane], a1);
                    unsafeAtomicAdd(&agV2[cur * 384 + 2 * 128 + lane], a2);
                    a0 = a1 = a2 = 0.f;
                } else if (mu == 2) {
                    unsafeAtomicAdd(&agV2[cur * 384 + 0 * 128 + 64 + lane], a0);
                    unsafeAtomicAdd(&agV2[cur * 384 + 1 * 128 + 64 + lane], a1);
                    unsafeAtomicAdd(&agV2[cur * 384 + 2 * 128 + 64 + lane], a2);
                    a0 = a1 = a2 = 0.f;
                } else {
                    unsafeAtomicAdd(&agS2[cur * 128 + 64 + lane], accS); accS = 0.f;
                }
                cur = rcv;
            }
            if (mu == 0) {
                accS += tv * sUp2[snd * 64 + lane];
            } else if (mu == 1) {
                float msg = tv * sUp2[snd * 64 + lane];
                a0 += msg * rl_f(y0A, e);
                a1 += msg * rl_f(y1A, e);
                a2 += msg * rl_f(y2A, e);
            } else if (mu == 2) {
                a0 += tv * vUp2[snd * 192 +       lane];
                a1 += tv * vUp2[snd * 192 +  64 + lane];
                a2 += tv * vUp2[snd * 192 + 128 + lane];
            } else {
                float v0 = vUp2[snd * 192 +       lane];
                float v1 = vUp2[snd * 192 +  64 + lane];
                float v2 = vUp2[snd * 192 + 128 + lane];
                accS += tv * (v0 * rl_f(y0A, e) + v1 * rl_f(y1A, e)
                            + v2 * rl_f(y2A, e)) * 0.577350269189626f;
            }
        }
    }
    if (mu == 0) {
        unsafeAtomicAdd(&agS2[cur * 128 + lane], accS);
    } else if (mu == 1) {
        unsafeAtomicAdd(&agV2[cur * 384 + 0 * 128 + lane], a0);
        unsafeAtomicAdd(&agV2[cur * 384 + 1 * 128 + lane], a1);
        unsafeAtomicAdd(&agV2[cur * 384 + 2 * 128 + lane], a2);
    } else if (mu == 2) {
        unsafeAtomicAdd(&agV2[cur * 384 + 0 * 128 + 64 + lane], a0);
        unsafeAtomicAdd(&agV2[cur * 384 + 1 * 128 + 64 + lane], a1);
        unsafeAtomicAdd(&agV2[cur * 384 + 2 * 128 + 64 + lane], a2);
    } else {
        unsafeAtomicAdd(&agS2[cur * 128 + 64 + lane], accS);
    }
}

// ---------------- node out ----------------
__global__ __launch_bounds__(256) void k_node_out(
    const float* __restrict__ L2s, const float* __restrict__ L2v,
    const float* __restrict__ agS2, const float* __restrict__ agV2,
    const float* __restrict__ skS2, const float* __restrict__ skV2,
    float* __restrict__ out)
{
    int lane = threadIdx.x & 63, wv = threadIdx.x >> 6;
    int n = blockIdx.x * 4 + wv;
    __shared__ __align__(16) float aS[4][128];
    __shared__ __align__(16) float aV[4][3][128];

    aS[wv][lane]      = agS2[n * 128 + lane];
    aS[wv][64 + lane] = agS2[n * 128 + 64 + lane];
    #pragma unroll
    for (int i = 0; i < 3; ++i) {
        aV[wv][i][lane]      = agV2[n * 384 + i * 128 + lane];
        aV[wv][i][64 + lane] = agV2[n * 384 + i * 128 + 64 + lane];
    }
    __syncthreads();

    float s2 = skS2[n * 64 + lane];
    #pragma unroll 8
    for (int u = 0; u < 128; ++u) s2 += aS[wv][u] * L2s[u * 64 + lane];
    float v2[3];
    #pragma unroll
    for (int i = 0; i < 3; ++i) v2[i] = skV2[n * 192 + i * 64 + lane];
    #pragma unroll 8
    for (int u = 0; u < 128; ++u) {
        float w = L2v[u * 64 + lane];
        v2[0] += aV[wv][0][u] * w;
        v2[1] += aV[wv][1][u] * w;
        v2[2] += aV[wv][2][u] * w;
    }
    out[(size_t)n * 256 + lane] = s2;
    #pragma unroll
    for (int i = 0; i < 3; ++i)
        out[(size_t)n * 256 + 64 + lane * 3 + i] = v2[i];
}

// ---------------- host launcher ----------------
extern "C" void kernel_launch(void* const* d_in, const int* in_sizes, int n_in,
                              void* d_out, int out_size, void* d_ws, size_t ws_size,
                              hipStream_t stream)
{
    (void)in_sizes; (void)n_in; (void)out_size; (void)ws_size;
    const float* positions  = (const float*)d_in[0];
    const float* node_attrs = (const float*)d_in[1];
    const int*   edge_index = (const int*)d_in[2];
    const float* shifts     = (const float*)d_in[3];
    const float* W_embed    = (const float*)d_in[4];
    const float* R1W1 = (const float*)d_in[5];
    const float* R1W2 = (const float*)d_in[6];
    const float* R1W3 = (const float*)d_in[7];
    const float* U1s  = (const float*)d_in[8];
    const float* L1s  = (const float*)d_in[9];
    const float* L1v  = (const float*)d_in[10];
    const float* K1s  = (const float*)d_in[11];
    const float* R2W1 = (const float*)d_in[12];
    const float* R2W2 = (const float*)d_in[13];
    const float* R2W3 = (const float*)d_in[14];
    const float* U2s  = (const float*)d_in[15];
    const float* U2v  = (const float*)d_in[16];
    const float* L2s  = (const float*)d_in[17];
    const float* L2v  = (const float*)d_in[18];
    const float* K2s  = (const float*)d_in[19];
    const float* K2v  = (const float*)d_in[20];

    float* wsf = (float*)d_ws;
    int*   wsi = (int*)(wsf + OFF_INT);
    int* hist   = wsi;
    int* cursor = wsi + 20000;
    int* sorted = wsi + 40000;
    unsigned short* wsh = (unsigned short*)(wsi + 360000);
    const unsigned short* w3a_hi = wsh;
    const unsigned short* w3a_lo = wsh + 8192;
    const unsigned short* w3b_hi = wsh + 16384;
    const unsigned short* w3b_lo = wsh + 32768;

    hipMemsetAsync(wsf + OFF_AGS1, 0, (size_t)4 * NC * sizeof(float), stream);
    hipMemsetAsync(hist, 0, 20000 * sizeof(int), stream);

    k_wsplit<<<96, 256, 0, stream>>>(R1W3, R2W3, wsh);
    k_hist<<<NEDGES / 256, 256, 0, stream>>>(edge_index, hist);
    k_scan<<<1, 1024, 0, stream>>>(hist, cursor);
    k_scatter<<<NEDGES / 256, 256, 0, stream>>>(edge_index, cursor, sorted);

    k_node_pre<<<NNODES / 4, 256, 0, stream>>>(node_attrs, W_embed, U1s, wsf + OFF_SUP1);
    k_edge1<<<NEDGES / 64, 256, 0, stream>>>(positions, edge_index, shifts, sorted,
                                             R1W1, R1W2, w3a_hi, w3a_lo,
                                             wsf + OFF_SUP1, wsf + OFF_AGS1, wsf + OFF_AGV1);
    k_node_mid<<<NNODES / 4, 256, 0, stream>>>(node_attrs, W_embed, K1s, L1s, L1v,
                                               U2s, U2v, K2s, K2v,
                                               wsf + OFF_AGS1, wsf + OFF_AGV1,
                                               wsf + OFF_SUP2, wsf + OFF_VUP2,
                                               wsf + OFF_SKS2, wsf + OFF_SKV2);
    hipMemsetAsync(wsf + OFF_AGS2, 0, (size_t)8 * NC * sizeof(float), stream);
    k_edge2<<<NEDGES / 64, 256, 0, stream>>>(positions, edge_index, shifts, sorted,
                                             R2W1, R2W2, w3b_hi, w3b_lo,
                                             wsf + OFF_SUP2, wsf + OFF_VUP2,
                                             wsf + OFF_AGS2, wsf + OFF_AGV2);
    k_node_out<<<NNODES / 4, 256, 0, stream>>>(L2s, L2v, wsf + OFF_AGS2, wsf + OFF_AGV2,
                                               wsf + OFF_SKS2, wsf + OFF_SKV2,
                                               (float*)d_out);
}